// Round 6
// baseline (487.768 us; speedup 1.0000x reference)
//
#include <hip/hip_runtime.h>
#include <stdint.h>

#define T_DIM 8192
#define C_DIM 2048
#define LCHUNK 128
#define NCHUNK (T_DIM / LCHUNK)

typedef unsigned short u16;
typedef __bf16 bf16x8_t __attribute__((ext_vector_type(8)));
typedef float f32x4_t __attribute__((ext_vector_type(4)));

__device__ __forceinline__ u16 f2bf(float f) {
    union { float f; uint32_t u; } x; x.f = f;
    uint32_t r = x.u + 0x7fffu + ((x.u >> 16) & 1u);
    return (u16)(r >> 16);
}
__device__ __forceinline__ float bf2f(u16 u) {
    union { uint32_t u; float f; } x; x.u = ((uint32_t)u) << 16;
    return x.f;
}
__device__ __forceinline__ void gload16(const void* g, void* l) {
    __builtin_amdgcn_global_load_lds((const __attribute__((address_space(1))) uint32_t*)g,
                                     (__attribute__((address_space(3))) uint32_t*)l, 16, 0, 0);
}
__device__ __forceinline__ f32x4_t mfma16(bf16x8_t a, bf16x8_t b, f32x4_t c) {
    return __builtin_amdgcn_mfma_f32_16x16x32_bf16(a, b, c, 0, 0, 0);
}

// ---------------- transpose + cast weights: Wt[n][k] = bf16(W[k][n]) ----------------
__global__ __launch_bounds__(256)
void transpose_cast(const float* __restrict__ W0, const float* __restrict__ W1,
                    const float* __restrict__ W2, const float* __restrict__ W3,
                    u16* __restrict__ Wt)
{
    __shared__ float tile[32][33];
    const int z = blockIdx.z;
    const float* W = (z == 0) ? W0 : (z == 1) ? W1 : (z == 2) ? W2 : W3;
    u16* Tm = Wt + (size_t)z * C_DIM * C_DIM;
    const int tx = threadIdx.x & 31, ty = threadIdx.x >> 5;
    const int bn = blockIdx.x * 32, bk = blockIdx.y * 32;
#pragma unroll
    for (int i = 0; i < 4; ++i)
        tile[ty + 8 * i][tx] = W[(size_t)(bk + ty + 8 * i) * C_DIM + bn + tx];
    __syncthreads();
#pragma unroll
    for (int i = 0; i < 4; ++i)
        Tm[(size_t)(bn + ty + 8 * i) * C_DIM + bk + tx] = f2bf(tile[tx][ty + 8 * i]);
}

// ---------------- LayerNorm(row t) + LayerNorm(row t-1) + token-shift mix -> bf16 ----------------
union F8 { float4 v[2]; float f[8]; };

__global__ __launch_bounds__(256)
void ln_mix_kernel(const float* __restrict__ x, const float* __restrict__ sx,
                   const float* __restrict__ lns, const float* __restrict__ lnb,
                   const float* __restrict__ tmk, const float* __restrict__ tmv,
                   const float* __restrict__ tmr,
                   u16* __restrict__ kx, u16* __restrict__ vx, u16* __restrict__ rx,
                   float* __restrict__ xx_last)
{
    const int t = blockIdx.x;
    const int tid = threadIdx.x;
    const size_t rowoff = (size_t)t * C_DIM;

    F8 a, p;
    const float4* xt = (const float4*)(x + rowoff);
    a.v[0] = xt[2 * tid]; a.v[1] = xt[2 * tid + 1];
    const float4* xp = (t == 0) ? (const float4*)sx : (const float4*)(x + rowoff - C_DIM);
    p.v[0] = xp[2 * tid]; p.v[1] = xp[2 * tid + 1];

    float s1 = 0.f, s2 = 0.f, s3 = 0.f, s4 = 0.f;
#pragma unroll
    for (int i = 0; i < 8; ++i) {
        s1 += a.f[i]; s2 += a.f[i] * a.f[i];
        s3 += p.f[i]; s4 += p.f[i] * p.f[i];
    }
#pragma unroll
    for (int off = 32; off; off >>= 1) {
        s1 += __shfl_down(s1, off);
        s2 += __shfl_down(s2, off);
        s3 += __shfl_down(s3, off);
        s4 += __shfl_down(s4, off);
    }
    __shared__ float red[4][4];
    if ((tid & 63) == 0) {
        red[0][tid >> 6] = s1; red[1][tid >> 6] = s2;
        red[2][tid >> 6] = s3; red[3][tid >> 6] = s4;
    }
    __syncthreads();
    s1 = red[0][0] + red[0][1] + red[0][2] + red[0][3];
    s2 = red[1][0] + red[1][1] + red[1][2] + red[1][3];
    s3 = red[2][0] + red[2][1] + red[2][2] + red[2][3];
    s4 = red[3][0] + red[3][1] + red[3][2] + red[3][3];
    const float inv = 1.0f / (float)C_DIM;
    const float mu = s1 * inv;
    const float rstd = rsqrtf(s2 * inv - mu * mu + 1e-5f);
    const float mup = s3 * inv;
    const float rstdp = rsqrtf(s4 * inv - mup * mup + 1e-5f);

    F8 ls, lb, mk, mv, mr;
    { const float4* q = (const float4*)lns; ls.v[0] = q[2*tid]; ls.v[1] = q[2*tid+1]; }
    { const float4* q = (const float4*)lnb; lb.v[0] = q[2*tid]; lb.v[1] = q[2*tid+1]; }
    { const float4* q = (const float4*)tmk; mk.v[0] = q[2*tid]; mk.v[1] = q[2*tid+1]; }
    { const float4* q = (const float4*)tmv; mv.v[0] = q[2*tid]; mv.v[1] = q[2*tid+1]; }
    { const float4* q = (const float4*)tmr; mr.v[0] = q[2*tid]; mr.v[1] = q[2*tid+1]; }

    union { u16 u[8]; uint4 q; } ok, ov, orr;
#pragma unroll
    for (int i = 0; i < 8; ++i) {
        const float xxv  = (a.f[i] - mu) * rstd * ls.f[i] + lb.f[i];
        const float prev = (t == 0) ? p.f[i] : (p.f[i] - mup) * rstdp * ls.f[i] + lb.f[i];
        ok.u[i]  = f2bf(xxv * mk.f[i] + prev * (1.f - mk.f[i]));
        ov.u[i]  = f2bf(xxv * mv.f[i] + prev * (1.f - mv.f[i]));
        orr.u[i] = f2bf(xxv * mr.f[i] + prev * (1.f - mr.f[i]));
        if (t == T_DIM - 1) xx_last[tid * 8 + i] = xxv;
    }
    ((uint4*)(kx + rowoff))[tid] = ok.q;
    ((uint4*)(vx + rowoff))[tid] = ov.q;
    ((uint4*)(rx + rowoff))[tid] = orr.q;
}

// ---------------- bf16 GEMM, 256x128 tile, BK=32, dbuf, 2 blocks/CU ----------------
// C[M,N] = A[M,K]*Bt[N,K]^T. mode 0: f32 out (+resid), 1: bf16 out, 2: sigmoid->bf16 out.
// 256 thr = 4 waves (2M x 2N, 128x64 out each). LDS: 2 bufs x (A[256][32]+B[128][32]) = 48 KiB
// -> 2 independent blocks/CU (grid 512 = 2/CU): end-of-tile vmcnt(0) drain of one block is
// hidden by the other block's compute (m97/m114 implicit-TLP mechanism).
// Swizzle: 16B-slot s of row r holds global slot s^((r>>1)&3); applied on global src in
// staging (LDS linear, gload_lds constraint) and on ds_read addrs (2 lanes/bank -> free).
__global__ __launch_bounds__(256, 2)
void gemm_tile(const u16* __restrict__ A, const u16* __restrict__ Bt,
               void* __restrict__ Cout, const float* __restrict__ resid,
               const int mode, const int M, const int N, const int K)
{
    __shared__ u16 lds[2 * 12288];
    const int tid = threadIdx.x;
    const int wave = tid >> 6, lane = tid & 63;
    const int nbm = M >> 8;                     // m-fast: XCD round-robin keeps A-panel on one XCD
    const int m0 = (int)(blockIdx.x % nbm) << 8;
    const int n0 = (int)(blockIdx.x / nbm) << 7;
    const int wm = wave >> 1, wn = wave & 1;
    const int fr = lane & 15, fo = lane >> 4;
    const int sw = (fo ^ ((fr >> 1) & 3)) * 8;  // swizzled 16B-slot (u16 units)

    f32x4_t acc[8][4] = {};

    // staging: wave w covers rows w*16 + (lane>>2), slot lane&3 (linear dest);
    // global source column pre-swizzled by ^((row>>1)&3) = ^((lane>>3)&3).
    const int lrow = lane >> 2;
    const int scol = ((lane & 3) ^ ((lane >> 3) & 3)) * 8;
    const u16* gA = A  + (size_t)(m0 + wave * 16 + lrow) * K + scol;
    const u16* gB = Bt + (size_t)(n0 + wave * 16 + lrow) * K + scol;
    const int dstw = wave * 512;

    auto stage = [&](int t) {
        const int b = (t & 1) * 12288;
        const u16* ga = gA + (size_t)t * 32;
        const u16* gb = gB + (size_t)t * 32;
        gload16(ga,                   lds + b + dstw);          // A rows   0- 63
        gload16(ga + (size_t)64 * K,  lds + b + 2048 + dstw);   // A rows  64-127
        gload16(ga + (size_t)128 * K, lds + b + 4096 + dstw);   // A rows 128-191
        gload16(ga + (size_t)192 * K, lds + b + 6144 + dstw);   // A rows 192-255
        gload16(gb,                   lds + b + 8192 + dstw);   // B rows   0- 63
        gload16(gb + (size_t)64 * K,  lds + b + 10240 + dstw);  // B rows  64-127
    };

    const int NT = K >> 5;
    stage(0);
    asm volatile("s_waitcnt vmcnt(0)" ::: "memory");
    asm volatile("s_barrier" ::: "memory");

    for (int t = 0; t < NT; ++t) {
        if (t + 1 < NT) stage(t + 1);           // issue next tile's loads first
        const u16* lA = lds + (t & 1) * 12288 + (wm * 128 + fr) * 32;
        const u16* lB = lds + (t & 1) * 12288 + 8192 + (wn * 64 + fr) * 32;
        bf16x8_t a[8], b[4];
#pragma unroll
        for (int mi = 0; mi < 8; ++mi) a[mi] = *(const bf16x8_t*)(lA + mi * 512 + sw);
#pragma unroll
        for (int ni = 0; ni < 4; ++ni) b[ni] = *(const bf16x8_t*)(lB + ni * 512 + sw);
        __builtin_amdgcn_s_setprio(1);
#pragma unroll
        for (int mi = 0; mi < 8; ++mi)
#pragma unroll
            for (int ni = 0; ni < 4; ++ni)
                acc[mi][ni] = mfma16(a[mi], b[ni], acc[mi][ni]);
        __builtin_amdgcn_s_setprio(0);
        asm volatile("s_waitcnt vmcnt(0)" ::: "memory");   // t+1 landed (drain hidden by 2nd block)
        asm volatile("s_barrier" ::: "memory");
    }

    const int r4 = fo * 4;
#pragma unroll
    for (int mi = 0; mi < 8; ++mi) {
#pragma unroll
        for (int ni = 0; ni < 4; ++ni) {
            const int col = n0 + wn * 64 + ni * 16 + fr;
#pragma unroll
            for (int i = 0; i < 4; ++i) {
                const int row = m0 + wm * 128 + mi * 16 + r4 + i;
                float v = acc[mi][ni][i];
                if (resid) v += resid[(size_t)row * N + col];
                if (mode == 0)      ((float*)Cout)[(size_t)row * N + col] = v;
                else if (mode == 1) ((u16*)Cout)[(size_t)row * N + col] = f2bf(v);
                else {
                    const float s = 1.f / (1.f + __expf(-v));
                    ((u16*)Cout)[(size_t)row * N + col] = f2bf(s);
                }
            }
        }
    }
}

// ---------------- WKV scan, chunked ----------------
__global__ __launch_bounds__(256)
void scan_partial(const float* __restrict__ k, const u16* __restrict__ v,
                  const float* __restrict__ time_decay,
                  float* __restrict__ pA, float* __restrict__ pB, float* __restrict__ pP)
{
    const int c = blockIdx.y * 256 + threadIdx.x;
    const int j = blockIdx.x;
    const float w = -__expf(time_decay[c]);
    float aa = 0.f, bb = 0.f, pp = -1e30f;
    const float* kp = k + (size_t)j * LCHUNK * C_DIM + c;
    const u16*  vp = v + (size_t)j * LCHUNK * C_DIM + c;
#pragma unroll 4
    for (int i = 0; i < LCHUNK; ++i) {
        const float kk = *kp;
        const float vv = bf2f(*vp);
        kp += C_DIM; vp += C_DIM;
        const float ww = w + pp;
        const float p2 = fmaxf(ww, kk);
        const float e1 = __expf(ww - p2);
        const float e2 = __expf(kk - p2);
        aa = e1 * aa + e2 * vv;
        bb = e1 * bb + e2;
        pp = p2;
    }
    const int o = j * C_DIM + c;
    pA[o] = aa; pB[o] = bb; pP[o] = pp;
}

__global__ __launch_bounds__(256)
void scan_combine(const float* __restrict__ pA, const float* __restrict__ pB,
                  const float* __restrict__ pP,
                  const float* __restrict__ aa_in, const float* __restrict__ bb_in,
                  const float* __restrict__ pp_in,
                  const float* __restrict__ time_decay,
                  float* __restrict__ sA, float* __restrict__ sB, float* __restrict__ sP)
{
    const int c = blockIdx.x * 256 + threadIdx.x;
    const float wL = -__expf(time_decay[c]) * (float)LCHUNK;
    float a = aa_in[c], b = bb_in[c], p = pp_in[c];
    for (int j = 0; j < NCHUNK; ++j) {
        const int o = j * C_DIM + c;
        sA[o] = a; sB[o] = b; sP[o] = p;
        const float A = pA[o], B = pB[o], P = pP[o];
        const float pd = p + wL;
        const float q = fmaxf(pd, P);
        const float e1 = __expf(pd - q), e2 = __expf(P - q);
        a = e1 * a + e2 * A;
        b = e1 * b + e2 * B;
        p = q;
    }
}

__global__ __launch_bounds__(256)
void scan_out(const float* __restrict__ k, const u16* __restrict__ v,
              const u16* __restrict__ r,   // sigmoid(rx@Wr) pre-applied, bf16
              const float* __restrict__ time_decay, const float* __restrict__ time_first,
              const float* __restrict__ sA, const float* __restrict__ sB,
              const float* __restrict__ sP,
              u16* __restrict__ arwkv,
              float* __restrict__ aa_out, float* __restrict__ bb_out, float* __restrict__ pp_out)
{
    const int c = blockIdx.y * 256 + threadIdx.x;
    const int j = blockIdx.x;
    const float w = -__expf(time_decay[c]);
    const float u = time_first[c];
    const int so = j * C_DIM + c;
    float aa = sA[so], bb = sB[so], pp = sP[so];
    const size_t base = (size_t)j * LCHUNK * C_DIM + c;
    const float* kp = k + base;
    const u16*  vp = v + base;
    const u16*  rp = r + base;
    u16* op = arwkv + base;
#pragma unroll 4
    for (int i = 0; i < LCHUNK; ++i) {
        const float kk = *kp;
        const float vv = bf2f(*vp);
        const float sr = bf2f(*rp);
        kp += C_DIM; vp += C_DIM; rp += C_DIM;
        const float ww = u + kk;
        const float p = fmaxf(pp, ww);
        const float e1 = __expf(pp - p);
        const float e2 = __expf(ww - p);
        const float out = (e1 * aa + e2 * vv) / (e1 * bb + e2);
        *op = f2bf(sr * out);
        op += C_DIM;
        const float ww2 = w + pp;
        const float p2 = fmaxf(ww2, kk);
        const float f1 = __expf(ww2 - p2);
        const float f2 = __expf(kk - p2);
        aa = f1 * aa + f2 * vv;
        bb = f1 * bb + f2;
        pp = p2;
    }
    if (j == NCHUNK - 1) { aa_out[c] = aa; bb_out[c] = bb; pp_out[c] = pp; }
}

// ---------------- launcher ----------------
extern "C" void kernel_launch(void* const* d_in, const int* in_sizes, int n_in,
                              void* d_out, int out_size, void* d_ws, size_t ws_size,
                              hipStream_t stream)
{
    (void)in_sizes; (void)n_in; (void)out_size; (void)ws_size;
    const float* x          = (const float*)d_in[0];
    const float* sx         = (const float*)d_in[1];
    const float* aa_in      = (const float*)d_in[2];
    const float* bb_in      = (const float*)d_in[3];
    const float* pp_in      = (const float*)d_in[4];
    const float* time_first = (const float*)d_in[5];
    const float* time_decay = (const float*)d_in[6];
    const float* tmk        = (const float*)d_in[7];
    const float* tmv        = (const float*)d_in[8];
    const float* tmr        = (const float*)d_in[9];
    const float* lns        = (const float*)d_in[10];
    const float* lnb        = (const float*)d_in[11];
    const float* Wk         = (const float*)d_in[12];
    const float* Wv         = (const float*)d_in[13];
    const float* Wr         = (const float*)d_in[14];
    const float* Wo         = (const float*)d_in[15];

    float* out     = (float*)d_out;
    float* xx_last = out + (size_t)T_DIM * C_DIM;
    float* aa_out  = xx_last + C_DIM;
    float* bb_out  = aa_out + C_DIM;
    float* pp_out  = bb_out + C_DIM;

    const size_t TC = (size_t)T_DIM * C_DIM;
    const size_t C2 = (size_t)C_DIM * C_DIM;
    u16* kx    = (u16*)d_ws;
    u16* vx    = kx + TC;
    u16* rx    = vx + TC;
    u16* Wt    = rx + TC;                  // 4*C2 bf16
    float* kbuf = (float*)(Wt + 4 * C2);   // TC f32
    u16* vbuf   = (u16*)(kbuf + TC);       // TC bf16
    float* pA   = (float*)(vbuf + TC);
    float* pB   = pA + (size_t)NCHUNK * C_DIM;
    float* pP   = pB + (size_t)NCHUNK * C_DIM;
    float* sA   = pP + (size_t)NCHUNK * C_DIM;
    float* sB   = sA + (size_t)NCHUNK * C_DIM;
    float* sP   = sB + (size_t)NCHUNK * C_DIM;
    u16* rbuf   = kx;   // alias: kx dead after k-GEMM; r stored as bf16 sigmoid
    u16* arwkv  = rx;   // alias: rx dead after r-GEMM

    transpose_cast<<<dim3(C_DIM / 32, C_DIM / 32, 4), 256, 0, stream>>>(Wk, Wv, Wr, Wo, Wt);
    ln_mix_kernel<<<T_DIM, 256, 0, stream>>>(x, sx, lns, lnb, tmk, tmv, tmr, kx, vx, rx, xx_last);

    const int NWG = (T_DIM / 256) * (C_DIM / 128);   // 32 x 16 = 512 blocks = 2/CU
    gemm_tile<<<NWG, 256, 0, stream>>>(kx, Wt + 0 * C2, kbuf, nullptr, 0, T_DIM, C_DIM, C_DIM);
    gemm_tile<<<NWG, 256, 0, stream>>>(vx, Wt + 1 * C2, vbuf, nullptr, 1, T_DIM, C_DIM, C_DIM);
    gemm_tile<<<NWG, 256, 0, stream>>>(rx, Wt + 2 * C2, rbuf, nullptr, 2, T_DIM, C_DIM, C_DIM);

    scan_partial<<<dim3(NCHUNK, C_DIM / 256), 256, 0, stream>>>(kbuf, vbuf, time_decay, pA, pB, pP);
    scan_combine<<<C_DIM / 256, 256, 0, stream>>>(pA, pB, pP, aa_in, bb_in, pp_in, time_decay, sA, sB, sP);
    scan_out<<<dim3(NCHUNK, C_DIM / 256), 256, 0, stream>>>(kbuf, vbuf, rbuf, time_decay, time_first,
                                                            sA, sB, sP, arwkv, aa_out, bb_out, pp_out);

    gemm_tile<<<NWG, 256, 0, stream>>>(arwkv, Wt + 3 * C2, out, x, 0, T_DIM, C_DIM, C_DIM);
}